// Round 2
// baseline (151.118 us; speedup 1.0000x reference)
//
#include <hip/hip_runtime.h>

#define EMBED 128
#define NEG 5

__global__ __launch_bounds__(256) void sgneg_kernel(
    const int* __restrict__ pos_w,
    const int* __restrict__ pos_v,
    const int* __restrict__ neg_v,
    const float* __restrict__ w_table,
    const float* __restrict__ v_table,
    float* __restrict__ out,
    int batch)
{
    const int lane32 = threadIdx.x & 31;
    const int groupInBlock = threadIdx.x >> 5;     // 0..7 for 256-thread block
    const int groupsPerBlock = blockDim.x >> 5;    // 8
    const int group = blockIdx.x * groupsPerBlock + groupInBlock;
    const int nGroups = gridDim.x * groupsPerBlock;

    float acc = 0.0f;

    for (int b = group; b < batch; b += nGroups) {
        const int iw  = pos_w[b];
        const int ipv = pos_v[b];
        const int in0 = neg_v[b * NEG + 0];
        const int in1 = neg_v[b * NEG + 1];
        const int in2 = neg_v[b * NEG + 2];
        const int in3 = neg_v[b * NEG + 3];
        const int in4 = neg_v[b * NEG + 4];

        const size_t off = (size_t)lane32 * 4;
        const float4 w  = *reinterpret_cast<const float4*>(w_table + (size_t)iw  * EMBED + off);
        const float4 pv = *reinterpret_cast<const float4*>(v_table + (size_t)ipv * EMBED + off);
        const float4 n0 = *reinterpret_cast<const float4*>(v_table + (size_t)in0 * EMBED + off);
        const float4 n1 = *reinterpret_cast<const float4*>(v_table + (size_t)in1 * EMBED + off);
        const float4 n2 = *reinterpret_cast<const float4*>(v_table + (size_t)in2 * EMBED + off);
        const float4 n3 = *reinterpret_cast<const float4*>(v_table + (size_t)in3 * EMBED + off);
        const float4 n4 = *reinterpret_cast<const float4*>(v_table + (size_t)in4 * EMBED + off);

        float d0 = fmaf(w.x, pv.x, fmaf(w.y, pv.y, fmaf(w.z, pv.z, w.w * pv.w)));
        float d1 = fmaf(w.x, n0.x, fmaf(w.y, n0.y, fmaf(w.z, n0.z, w.w * n0.w)));
        float d2 = fmaf(w.x, n1.x, fmaf(w.y, n1.y, fmaf(w.z, n1.z, w.w * n1.w)));
        float d3 = fmaf(w.x, n2.x, fmaf(w.y, n2.y, fmaf(w.z, n2.z, w.w * n2.w)));
        float d4 = fmaf(w.x, n3.x, fmaf(w.y, n3.y, fmaf(w.z, n3.z, w.w * n3.w)));
        float d5 = fmaf(w.x, n4.x, fmaf(w.y, n4.y, fmaf(w.z, n4.z, w.w * n4.w)));

        // Butterfly reduce across the 32-lane group (masks <32 stay within
        // each half of the wave64).
        #pragma unroll
        for (int m = 16; m >= 1; m >>= 1) {
            d0 += __shfl_xor(d0, m, 64);
            d1 += __shfl_xor(d1, m, 64);
            d2 += __shfl_xor(d2, m, 64);
            d3 += __shfl_xor(d3, m, 64);
            d4 += __shfl_xor(d4, m, 64);
            d5 += __shfl_xor(d5, m, 64);
        }

        if (lane32 == 0) {
            // loss contribution = -log_sigmoid(clip(s1)) - sum_k log_sigmoid(-clip(s2k))
            //                   = log1p(exp(-clip(s1))) + sum_k log1p(exp(clip(s2k)))
            float s1 = fminf(10.0f, fmaxf(-10.0f, d0));
            acc += log1pf(__expf(-s1));
            float s;
            s = fminf(10.0f, fmaxf(-10.0f, d1)); acc += log1pf(__expf(s));
            s = fminf(10.0f, fmaxf(-10.0f, d2)); acc += log1pf(__expf(s));
            s = fminf(10.0f, fmaxf(-10.0f, d3)); acc += log1pf(__expf(s));
            s = fminf(10.0f, fmaxf(-10.0f, d4)); acc += log1pf(__expf(s));
            s = fminf(10.0f, fmaxf(-10.0f, d5)); acc += log1pf(__expf(s));
        }
    }

    // Per-block reduction: lane 0 of each 32-lane group holds a partial.
    __shared__ float sacc[8];
    if (lane32 == 0) sacc[groupInBlock] = acc;
    __syncthreads();
    if (threadIdx.x == 0) {
        float t = 0.0f;
        #pragma unroll
        for (int i = 0; i < 8; ++i) t += sacc[i];
        atomicAdd(out, t);
    }
}

extern "C" void kernel_launch(void* const* d_in, const int* in_sizes, int n_in,
                              void* d_out, int out_size, void* d_ws, size_t ws_size,
                              hipStream_t stream) {
    const int*   pos_w   = (const int*)d_in[0];
    const int*   pos_v   = (const int*)d_in[1];
    const int*   neg_v   = (const int*)d_in[2];
    const float* w_table = (const float*)d_in[3];
    const float* v_table = (const float*)d_in[4];
    float* out = (float*)d_out;

    const int batch = in_sizes[0];

    // d_out is poisoned to 0xAA before every timed launch — zero it.
    hipMemsetAsync(out, 0, sizeof(float), stream);

    const int blocks = 2048;   // 16384 groups -> 4 rows per group via grid-stride
    sgneg_kernel<<<blocks, 256, 0, stream>>>(pos_w, pos_v, neg_v,
                                             w_table, v_table, out, batch);
}